// Round 8
// baseline (326.925 us; speedup 1.0000x reference)
//
#include <hip/hip_runtime.h>

// Conv_Attention: q,k,v = causal_conv1d(x, W*) ; S = qk^T/sqrt(U);
// softmax over QUERY axis (per-column of S); out = P @ v.
// B=8, T=2048, Cin=U=512, K=3.
//
// Round 8 structure:
//  1. setup (ONE kernel): prep_x (xpad bf16), Wq/Wk/Wv transpose -> Wt, bias concat
//  2. QKV GEMM (N=1536): n-blocks 0..7 write Q,K to QKV [B][T][1536];
//     n-blocks 8..11 (V) write DIRECTLY TRANSPOSED to Vt [B][512][2048] via an
//     LDS bounce in the epilogue (transpose_v pass deleted: -67 MB RW, -1 dispatch)
//  3. scores GEMM: epilogue stores P_raw = bf16(exp(S*scale-16)) + partial colsums
//  4. stats_combine: inv[k] = 1/L[k]
//  5. scale_vt: Vt[d][k] *= inv[k]
//  6. ctx GEMM 64x128 tiles -> out fp32
//
// GEMM core (frozen since R7): 32x32x16 MFMA, BK=32, 128-wide tiles,
// global_load_lds width=16 staging, XOR chunk swizzle (q ^= (row>>1)&3).
// Known plateau: ~716 TF on QKV (m97-structure barrier-drain bound; BK=64,
// launch_bounds, MFMA-shape changes all neutral-or-worse in R3/R5/R6).

#define B_   8
#define T_   2048
#define D_   512
#define KC_  1536
#define TPAD_ 2050

using short8   = __attribute__((ext_vector_type(8))) short;
using float4v  = __attribute__((ext_vector_type(4))) float;
using int4v    = __attribute__((ext_vector_type(4))) int;
using float16v = __attribute__((ext_vector_type(16))) float;

__device__ __forceinline__ float bf2f(unsigned short b) {
  unsigned u = ((unsigned)b) << 16;
  float f; __builtin_memcpy(&f, &u, 4); return f;
}
__device__ __forceinline__ unsigned short f2bf(float f) {
  unsigned u; __builtin_memcpy(&u, &f, 4);
  u += 0x7fffu + ((u >> 16) & 1u);          // RNE (finite inputs only)
  return (unsigned short)(u >> 16);
}

__device__ __forceinline__ void gld16(const void* g, void* l) {
  __builtin_amdgcn_global_load_lds((__attribute__((address_space(1))) void*)g,
                                   (__attribute__((address_space(3))) void*)l,
                                   16, 0, 0);
}

// ---------------- setup: prep_x + W transpose + bias concat, one launch ----------------
// blocks [0,8200): prep_x ; [8200,8776): W transpose (192/z) ; [8776,8782): bias
__global__ __launch_bounds__(256) void setup(const float* __restrict__ x,
                                             const float* __restrict__ Wq,
                                             const float* __restrict__ Wk,
                                             const float* __restrict__ Wv,
                                             const float* __restrict__ bq,
                                             const float* __restrict__ bk,
                                             const float* __restrict__ bv,
                                             unsigned short* __restrict__ xpad,
                                             unsigned short* __restrict__ Wt,
                                             float* __restrict__ bcat) {
  __shared__ unsigned short tile[64][65];
  const int bx = blockIdx.x;
  if (bx < 8200) {
    const int b = bx / 1025;
    const int rem = bx - b * 1025;
    const int i = (rem * 256 + threadIdx.x) * 4;   // < 2050*512
    const int t = i >> 9;
    unsigned short* dst = xpad + (size_t)b * (TPAD_ * D_) + i;
    if (t < 2) {
      dst[0] = 0; dst[1] = 0; dst[2] = 0; dst[3] = 0;
    } else {
      const float* sp = x + ((size_t)b * T_ + (t - 2)) * D_ + (i & 511);
      float4v v = *(const float4v*)sp;
      dst[0] = f2bf(v[0]); dst[1] = f2bf(v[1]); dst[2] = f2bf(v[2]); dst[3] = f2bf(v[3]);
    }
  } else if (bx < 8776) {
    const int tt = bx - 8200;
    const int z = tt / 192;
    const int r = tt - z * 192;
    const float* s = (z == 0) ? Wq : (z == 1) ? Wk : Wv;   // [1536 k][512 u]
    unsigned short* d = Wt + (size_t)z * D_ * KC_;          // [512 u][1536 k]
    const int r0 = (r >> 3) * 64, c0 = (r & 7) * 64;
    const int tc = threadIdx.x & 63, tg = threadIdx.x >> 6;
#pragma unroll
    for (int i = 0; i < 16; i++) {
      const int rr = i * 4 + tg;
      tile[rr][tc] = f2bf(s[(size_t)(r0 + rr) * D_ + (c0 + tc)]);
    }
    __syncthreads();
#pragma unroll
    for (int i = 0; i < 16; i++) {
      const int rr = i * 4 + tg;
      d[(size_t)(c0 + rr) * KC_ + (r0 + tc)] = tile[tc][rr];
    }
  } else {
    const int i = (bx - 8776) * 256 + threadIdx.x;   // 0..1535
    float v = (i < 512) ? bq[i] : ((i < 1024) ? bk[i - 512] : bv[i - 1024]);
    bcat[i] = v;
  }
}

// ---------------- combine: inv[k] = 1 / sum of partial colsums ----------------
__global__ __launch_bounds__(256) void stats_combine(const float* __restrict__ pl,
                                                     long long sPz,
                                                     float* __restrict__ inv,
                                                     long long sIz) {
  const size_t z = blockIdx.z;
  const int col = blockIdx.x * 256 + threadIdx.x;
  float L = 0.f;
#pragma unroll
  for (int mb = 0; mb < 16; mb++)
    L += pl[z * (size_t)sPz + (size_t)mb * T_ + col];
  inv[z * (size_t)sIz + col] = 1.0f / L;
}

// ---------------- scale Vt rows: Vt[d][k] *= inv[k] ----------------
__global__ __launch_bounds__(256) void scale_vt(unsigned short* __restrict__ Vt,
                                                long long sVz,
                                                const float* __restrict__ inv,
                                                long long sIz) {
  const size_t z = blockIdx.z;
  unsigned short* Vb = Vt + z * (size_t)sVz;
  const float* iv = inv + z * (size_t)sIz;
  const int idx = (blockIdx.x * 256 + threadIdx.x) * 8;  // grid.x=512 -> 512*2048
  const int k = idx & (T_ - 1);
  short8 v = *(const short8*)(Vb + idx);
  float4v i0 = *(const float4v*)(iv + k);
  float4v i1 = *(const float4v*)(iv + k + 4);
  short8 o;
#pragma unroll
  for (int j = 0; j < 8; j++) {
    float s = (j < 4) ? i0[j & 3] : i1[j & 3];
    o[j] = (short)f2bf(bf2f((unsigned short)v[j]) * s);
  }
  *(short8*)(Vb + idx) = o;
}

// ---------------- unified GEMM: C = A * B'^T  (BK=32, 32x32x16 MFMA) ----------------
// A [M][K] bf16 row-major (lda), B' [N][K] bf16 row-major (ldb), k-contiguous.
// MODE 0: bias add; n0<1024 -> bf16 to Out (QKV); n0>=1024 -> TRANSPOSED to vt
// MODE 1: P_raw = exp(v*scale-16) bf16 out + colsum (scores, 128x128)
// MODE 2: plain, fp32 out                           (ctx,     64x128)
template <int MODE>
__global__ __launch_bounds__(256)
void gemm_bt(const unsigned short* __restrict__ A, long long sAz, int lda,
             const unsigned short* __restrict__ Bm, long long sBz, int ldb,
             void* __restrict__ Out, long long sOz, int ldo,
             const float* __restrict__ bias,
             float* __restrict__ pl, long long sPz,
             unsigned short* __restrict__ vt, long long sVtz,
             int Kdim, float scale) {
  constexpr int MI = (MODE == 2) ? 1 : 2;   // 32-row subtiles per wave
  constexpr int BM = MI * 64;               // block m-extent (64 or 128)
  __shared__ unsigned short At[BM * 32];
  __shared__ unsigned short Bt[128 * 32];
  const int tid = threadIdx.x;
  const int lane = tid & 63;
  const int wave = tid >> 6;
  const int wm = wave >> 1, wn = wave & 1;
  const size_t z = blockIdx.z;
  const unsigned short* Ab = A + z * (size_t)sAz;
  const unsigned short* Bb = Bm + z * (size_t)sBz;
  const int m0 = blockIdx.x * BM, n0 = blockIdx.y * 128;

  float16v acc[MI][2];
#pragma unroll
  for (int mi = 0; mi < MI; mi++)
#pragma unroll
    for (int nj = 0; nj < 2; nj++)
#pragma unroll
      for (int r = 0; r < 16; r++) acc[mi][nj][r] = 0.f;

  // staging lane map: lane -> row rloc=lane>>2 (of 16), stored chunk qs=lane&3,
  // fetched global chunk = qs ^ ((row>>1)&3).
  const int rloc = lane >> 2, qs = lane & 3;
  const int rA = (MI == 2) ? (wave * 32 + rloc) : (wave * 16 + rloc);
  const int qgA = qs ^ ((rA >> 1) & 3);
  const unsigned short* gA0 = Ab + (size_t)(m0 + rA) * lda + qgA * 8;
  const unsigned short* gA1 = gA0 + (size_t)16 * lda;   // MI==2 only
  unsigned short* lA0 = At + ((MI == 2) ? wave * 1024 : wave * 512);
  unsigned short* lA1 = lA0 + 512;

  const int rB = wave * 32 + rloc;
  const int qgB = qs ^ ((rB >> 1) & 3);
  const unsigned short* gB0 = Bb + (size_t)(n0 + rB) * ldb + qgB * 8;
  const unsigned short* gB1 = gB0 + (size_t)16 * ldb;
  unsigned short* lB0 = Bt + wave * 1024;
  unsigned short* lB1 = lB0 + 512;

  // fragment read addressing: A/B operand [row = lane&31][k = (lane>>5)*8 + j]
  const int l31 = lane & 31;
  const int hi  = lane >> 5;
  int ar[MI], br[2];
#pragma unroll
  for (int mi = 0; mi < MI; mi++) ar[mi] = wm * (MI * 32) + mi * 32 + l31;
#pragma unroll
  for (int nj = 0; nj < 2; nj++) br[nj] = wn * 64 + nj * 32 + l31;

  for (int kk = 0; kk < Kdim; kk += 32) {
    gld16(gA0, lA0);
    if constexpr (MI == 2) gld16(gA1, lA1);
    gld16(gB0, lB0);
    gld16(gB1, lB1);
    __syncthreads();

#pragma unroll
    for (int h = 0; h < 2; h++) {
      const int qlog = h * 2 + hi;
      short8 af[MI], bfr[2];
#pragma unroll
      for (int mi = 0; mi < MI; mi++) {
        const int q = qlog ^ ((ar[mi] >> 1) & 3);
        af[mi] = *(const short8*)&At[ar[mi] * 32 + q * 8];
      }
#pragma unroll
      for (int nj = 0; nj < 2; nj++) {
        const int q = qlog ^ ((br[nj] >> 1) & 3);
        bfr[nj] = *(const short8*)&Bt[br[nj] * 32 + q * 8];
      }
#pragma unroll
      for (int mi = 0; mi < MI; mi++)
#pragma unroll
        for (int nj = 0; nj < 2; nj++)
          acc[mi][nj] = __builtin_amdgcn_mfma_f32_32x32x16_bf16(
              af[mi], bfr[nj], acc[mi][nj], 0, 0, 0);
    }
    __syncthreads();

    gA0 += 32; gB0 += 32; gB1 += 32;
    if constexpr (MI == 2) gA1 += 32;
  }

  // ---- MODE 0 V-blocks: transposed write to vt via LDS bounce ----
  if constexpr (MODE == 0) {
    __shared__ unsigned short Tr[128 * 34];   // [u][t(32) + pad2]: odd word stride
    if (n0 >= 1024) {
      float badd[2];
#pragma unroll
      for (int nj = 0; nj < 2; nj++) badd[nj] = bias[n0 + wn * 64 + nj * 32 + l31];
      unsigned short* vtb = vt + z * (size_t)sVtz;
#pragma unroll
      for (int p = 0; p < 4; p++) {           // t-rows m0+32p .. +32
        if (wm == (p >> 1)) {
          const int mi = p & 1;
#pragma unroll
          for (int nj = 0; nj < 2; nj++) {
            const int u = wn * 64 + nj * 32 + l31;
#pragma unroll
            for (int reg = 0; reg < 16; reg++) {
              const int t = (reg & 3) + 8 * (reg >> 2) + 4 * hi;
              Tr[u * 34 + t] = f2bf(acc[mi][nj][reg] * scale + badd[nj]);
            }
          }
        }
        __syncthreads();
#pragma unroll
        for (int it = 0; it < 2; it++) {
          const int u = (tid >> 2) + it * 64;
          const int t8 = (tid & 3) * 8;
          const int* sp = (const int*)(Tr + u * 34 + t8);
          int4v w = {sp[0], sp[1], sp[2], sp[3]};
          *(int4v*)(vtb + (size_t)(n0 - 1024 + u) * T_ + (m0 + 32 * p + t8)) = w;
        }
        __syncthreads();
      }
      return;
    }
  }

  // ---- normal epilogue: C/D col = lane&31, row = (reg&3)+8*(reg>>2)+4*(lane>>5) ----
  float cs[2] = {0.f, 0.f};
#pragma unroll
  for (int mi = 0; mi < MI; mi++) {
#pragma unroll
    for (int nj = 0; nj < 2; nj++) {
      const int col = n0 + wn * 64 + nj * 32 + l31;
      float badd = 0.f;
      if constexpr (MODE == 0) badd = bias[col];
#pragma unroll
      for (int reg = 0; reg < 16; reg++) {
        const int row = m0 + wm * (MI * 32) + mi * 32 + (reg & 3) + 8 * (reg >> 2) + 4 * hi;
        float v = acc[mi][nj][reg] * scale + badd;
        if constexpr (MODE == 2) {
          ((float*)Out)[z * (size_t)sOz + (size_t)row * ldo + col] = v;
        } else if constexpr (MODE == 1) {
          float e = __expf(v - 16.f);          // fixed shift; |v| <~ 25
          cs[nj] += e;
          ((unsigned short*)Out)[z * (size_t)sOz + (size_t)row * ldo + col] = f2bf(e);
        } else {
          ((unsigned short*)Out)[z * (size_t)sOz + (size_t)row * ldo + col] = f2bf(v);
        }
      }
    }
  }
  if constexpr (MODE == 1) {
    // column sums: xor-32 covers the 32 rows of a subtile; wm pair via LDS.
#pragma unroll
    for (int nj = 0; nj < 2; nj++) cs[nj] += __shfl_xor(cs[nj], 32, 64);
    float* red = (float*)At;
    if (wm == 1 && hi == 0) {
#pragma unroll
      for (int nj = 0; nj < 2; nj++) red[wn * 64 + nj * 32 + l31] = cs[nj];
    }
    __syncthreads();
    if (wm == 0 && hi == 0) {
#pragma unroll
      for (int nj = 0; nj < 2; nj++) {
        const int c = wn * 64 + nj * 32 + l31;
        pl[z * (size_t)sPz + (size_t)blockIdx.x * T_ + (n0 + c)] = cs[nj] + red[c];
      }
    }
  }
}

// ---------------- host ----------------
extern "C" void kernel_launch(void* const* d_in, const int* in_sizes, int n_in,
                              void* d_out, int out_size, void* d_ws, size_t ws_size,
                              hipStream_t stream) {
  const float* x  = (const float*)d_in[0];
  const float* Wq = (const float*)d_in[1];
  const float* bq = (const float*)d_in[2];
  const float* Wk = (const float*)d_in[3];
  const float* bk = (const float*)d_in[4];
  const float* Wv = (const float*)d_in[5];
  const float* bv = (const float*)d_in[6];

  char* ws = (char*)d_ws;
  auto alloc = [&](size_t bytes) {
    char* p = ws; ws += (bytes + 255) & ~(size_t)255; return p;
  };
  unsigned short* xpad = (unsigned short*)alloc((size_t)B_ * TPAD_ * D_ * 2);
  unsigned short* Wt   = (unsigned short*)alloc((size_t)KC_ * KC_ * 2);     // [1536 u][1536 k]
  float*          bcat = (float*)alloc((size_t)KC_ * 4);
  unsigned short* QKV  = (unsigned short*)alloc((size_t)B_ * T_ * KC_ * 2); // [B][T][1536] (V third unused)
  unsigned short* Vt   = (unsigned short*)alloc((size_t)B_ * D_ * T_ * 2);
  float* invb = (float*)alloc((size_t)B_ * T_ * 4);
  float* pl   = (float*)alloc((size_t)B_ * 16 * T_ * 4);
  size_t used = (size_t)(ws - (char*)d_ws);
  const size_t sAll = (size_t)B_ * T_ * T_ * 2;   // bf16 P, all batches
  const size_t sOne = (size_t)T_ * T_ * 2;
  const int NB = (used + sAll <= ws_size) ? B_ : 1;  // ws-adaptive batching
  unsigned short* Sb = (unsigned short*)alloc(NB == B_ ? sAll : sOne);

  setup<<<dim3(8782), 256, 0, stream>>>(x, Wq, Wk, Wv, bq, bk, bv, xpad, Wt, bcat);

  // QKV GEMM: M=2048/batch, N=1536, K=1536; V n-blocks write transposed to Vt
  gemm_bt<0><<<dim3(16, 12, B_), 256, 0, stream>>>(
      xpad, (long long)TPAD_ * D_, D_,
      Wt, 0, KC_,
      QKV, (long long)T_ * KC_, KC_,
      bcat, nullptr, 0,
      Vt, (long long)D_ * T_,
      KC_, 1.0f);

  const float scale = 0.044194173824159216f;  // 1/sqrt(512)
  for (int b0 = 0; b0 < B_; b0 += NB) {
    const unsigned short* Qp = QKV + (size_t)b0 * T_ * KC_;          // +0
    const unsigned short* Kp = QKV + (size_t)b0 * T_ * KC_ + D_;     // +512
    // P_raw = exp(S-16) + partial column sums
    gemm_bt<1><<<dim3(16, 16, NB), 256, 0, stream>>>(
        Qp, (long long)T_ * KC_, KC_,
        Kp, (long long)T_ * KC_, KC_,
        Sb, (long long)T_ * T_, T_,
        nullptr, pl + (size_t)b0 * 16 * T_, (long long)16 * T_,
        nullptr, 0,
        D_, scale);
    stats_combine<<<dim3(8, 1, NB), 256, 0, stream>>>(
        pl + (size_t)b0 * 16 * T_, (long long)16 * T_,
        invb + (size_t)b0 * T_, T_);
    scale_vt<<<dim3(512, 1, NB), 256, 0, stream>>>(
        Vt + (size_t)b0 * D_ * T_, (long long)D_ * T_,
        invb + (size_t)b0 * T_, T_);
    // ctx: out = P_raw @ Vt'^T, 64x128 tiles
    gemm_bt<2><<<dim3(32, 4, NB), 256, 0, stream>>>(
        Sb, (long long)T_ * T_, T_,
        Vt + (size_t)b0 * D_ * T_, (long long)D_ * T_, T_,
        (float*)d_out + (size_t)b0 * T_ * D_, (long long)T_ * D_, D_,
        nullptr, nullptr, 0,
        nullptr, 0,
        T_, 1.0f);
  }
}